// Round 1
// baseline (90.541 us; speedup 1.0000x reference)
//
#include <hip/hip_runtime.h>

// score[e] = dot(h[u[e]], h[v[e]]), h: [N_NODES, 128] f32, u/v: [N_EDGES] i32
// 16 lanes per edge: lane covers floats [lane*8, lane*8+8) via two float4 loads.

constexpr int D_FEAT = 128;
constexpr int LANES_PER_EDGE = 16;

__global__ __launch_bounds__(256) void edge_dot_kernel(
    const float* __restrict__ h,
    const int* __restrict__ u,
    const int* __restrict__ v,
    float* __restrict__ out,
    int n_edges)
{
    const int tid   = blockIdx.x * blockDim.x + threadIdx.x;
    const int lane  = threadIdx.x & (LANES_PER_EDGE - 1);
    const int group = tid / LANES_PER_EDGE;
    const int n_groups = (gridDim.x * blockDim.x) / LANES_PER_EDGE;

    for (int e = group; e < n_edges; e += n_groups) {
        const int ue = u[e];
        const int ve = v[e];

        const float4* hu = reinterpret_cast<const float4*>(h + (size_t)ue * D_FEAT) + lane * 2;
        const float4* hv = reinterpret_cast<const float4*>(h + (size_t)ve * D_FEAT) + lane * 2;

        float4 a0 = hu[0];
        float4 a1 = hu[1];
        float4 b0 = hv[0];
        float4 b1 = hv[1];

        float acc = a0.x * b0.x + a0.y * b0.y + a0.z * b0.z + a0.w * b0.w
                  + a1.x * b1.x + a1.y * b1.y + a1.z * b1.z + a1.w * b1.w;

        // Reduce across the 16-lane group (xor masks stay within the group).
        acc += __shfl_xor(acc, 8, 64);
        acc += __shfl_xor(acc, 4, 64);
        acc += __shfl_xor(acc, 2, 64);
        acc += __shfl_xor(acc, 1, 64);

        if (lane == 0) out[e] = acc;
    }
}

extern "C" void kernel_launch(void* const* d_in, const int* in_sizes, int n_in,
                              void* d_out, int out_size, void* d_ws, size_t ws_size,
                              hipStream_t stream) {
    const float* h = (const float*)d_in[0];
    const int*   u = (const int*)d_in[1];
    const int*   v = (const int*)d_in[2];
    float* out = (float*)d_out;

    const int n_edges = in_sizes[1];

    const int block = 256;
    // 2048 blocks * 4 waves = 8192 waves = full residency (256 CU * 32 waves).
    const int grid = 2048;

    edge_dot_kernel<<<grid, block, 0, stream>>>(h, u, v, out, n_edges);
}